// Round 8
// baseline (325.654 us; speedup 1.0000x reference)
//
#include <hip/hip_runtime.h>
#include <math.h>

#define NN 50000
#define EE 800000
#define GG 64
#define FD 128
#define OUTD 10
#define NB 49           // ceil(NN/1024) scan blocks
#define GB 782          // (NN+63)/64 gemm blocks
#define DB 3125         // EE/256 degree blocks
#define BB 196          // (NN+255)/256 bounds blocks
#define NP 8            // partial histogram copies

typedef __attribute__((ext_vector_type(8))) short s8v;    // 8 bf16
typedef __attribute__((ext_vector_type(4))) float f4v;    // 4 f32 acc

static __device__ inline unsigned short f2b(float f) {    // f32 -> bf16 RNE
    unsigned int u = __float_as_uint(f);
    return (unsigned short)((u + 0x7FFFu + ((u >> 16) & 1u)) >> 16);
}

// packed degree accumulator: bits [0,44) = sum(w) in 2^-32 fixed point,
// bits [44,64) = edge count. 8 partial copies to keep atomic lines XCD-local.
#define DEG_SCALE 4294967296.0
#define DEG_MASK  ((1ull << 44) - 1)

// ---------------- prep ----------------

__global__ void k_prep(unsigned long long* packed, const float* __restrict__ W1,
                       const float* __restrict__ W2, unsigned short* __restrict__ Wt1,
                       unsigned short* __restrict__ Wt2, int* __restrict__ bflag, int n) {
    int i = blockIdx.x * blockDim.x + threadIdx.x;
    if (i < n) {
        packed[i] = (1ull << 32);              // copy 0: cnt=0, deg=1.0 (self-loop weight)
        #pragma unroll
        for (int c = 1; c < NP; ++c) packed[(size_t)c * NN + i] = 0ull;
    }
    if (i < FD * FD) {
        int nn = i >> 7, k = i & 127;
        Wt1[i] = f2b(W1[k * FD + nn]);
        Wt2[i] = f2b(W2[k * FD + nn]);
    }
    if (i < NB) bflag[i] = 0;    // workspace is poisoned 0xAA -> must zero flags
}

// ---------------- mega kernel 1: gemm1 || degree atomics (8-way) || bounds ----------------

static __device__ inline void gemm_f32in_body(int bid, const float* __restrict__ A,
        const unsigned short* __restrict__ Wt, unsigned short* __restrict__ out, int n) {
    int tid = threadIdx.x;
    int wave = tid >> 6, lane = tid & 63;
    int quad = lane >> 4, c16 = lane & 15;
    int rowbase = bid * 64 + wave * 16;
    int rowA = rowbase + c16;
    if (rowA >= n) rowA = n - 1;
    f4v acc[8];
    #pragma unroll
    for (int t = 0; t < 8; ++t) acc[t] = (f4v){0.f, 0.f, 0.f, 0.f};
    #pragma unroll
    for (int k0 = 0; k0 < 128; k0 += 32) {
        const float* ap = A + (size_t)rowA * FD + k0 + quad * 8;
        float4 a0 = *(const float4*)ap;
        float4 a1 = *(const float4*)(ap + 4);
        s8v a;
        a[0] = (short)f2b(a0.x); a[1] = (short)f2b(a0.y);
        a[2] = (short)f2b(a0.z); a[3] = (short)f2b(a0.w);
        a[4] = (short)f2b(a1.x); a[5] = (short)f2b(a1.y);
        a[6] = (short)f2b(a1.z); a[7] = (short)f2b(a1.w);
        #pragma unroll
        for (int t = 0; t < 8; ++t) {
            s8v b = *(const s8v*)(Wt + (size_t)(t * 16 + c16) * FD + k0 + quad * 8);
            acc[t] = __builtin_amdgcn_mfma_f32_16x16x32_bf16(a, b, acc[t], 0, 0, 0);
        }
    }
    #pragma unroll
    for (int t = 0; t < 8; ++t) {
        #pragma unroll
        for (int r = 0; r < 4; ++r) {
            int row = rowbase + quad * 4 + r;
            if (row < n) out[(size_t)row * FD + t * 16 + c16] = f2b(acc[t][r]);
        }
    }
}

__global__ __launch_bounds__(256) void k_mega1(const float* __restrict__ x,
        const unsigned short* __restrict__ Wt1, unsigned short* __restrict__ hA,
        const int* __restrict__ dst, const float* __restrict__ ew,
        unsigned long long* packed, unsigned* __restrict__ rank,
        const int* __restrict__ batch, int* __restrict__ gstart) {
    int b = blockIdx.x;
    if (b < GB) {
        gemm_f32in_body(b, x, Wt1, hA, NN);
    } else if (b < GB + DB) {
        int i = (b - GB) * 256 + threadIdx.x;
        if (i < EE) {
            int c = b & (NP - 1);
            unsigned long long q = (unsigned long long)((double)ew[i] * DEG_SCALE + 0.5);
            unsigned long long old =
                atomicAdd(&packed[(size_t)c * NN + dst[i]], (1ull << 44) | q);
            rank[i] = ((unsigned)(old >> 44) << 3) | (unsigned)c;
        }
    } else {
        int i = (b - GB - DB) * 256 + threadIdx.x;
        if (i < NN) {
            int bb = batch[i];
            int bp = (i == 0) ? -1 : batch[i - 1];
            for (int g = bp + 1; g <= bb; ++g) gstart[g] = i;
            if (i == NN - 1)
                for (int g = bb + 1; g <= GG; ++g) gstart[g] = NN;
        }
    }
}

// ---------------- single-kernel scan (decoupled lookback) ----------------
// merges 8 partials, computes dinv + per-copy offsets, writes self-loop entry

__global__ __launch_bounds__(1024) void k_scan(const unsigned long long* __restrict__ packed,
        int* __restrict__ rowptr, float* __restrict__ dinv, uint2* __restrict__ ent,
        uint4* __restrict__ coffs, int* __restrict__ bsum, int* __restrict__ bflag, int n) {
    __shared__ int wtot[16];
    __shared__ int sbase_sh;
    int tid = threadIdx.x;
    int bid = blockIdx.x;
    int i = bid * 1024 + tid;
    int lane = tid & 63, wv = tid >> 6;

    int rowlen = 0;
    int v_edges = 0;
    float di = 0.0f;
    if (i < n) {
        unsigned long long degq = 0;
        int cnts[NP];
        #pragma unroll
        for (int c = 0; c < NP; ++c) {
            unsigned long long p = packed[(size_t)c * NN + i];
            cnts[c] = (int)(p >> 44);
            degq += p & DEG_MASK;
            v_edges += cnts[c];
        }
        float deg = (float)((double)degq * (1.0 / DEG_SCALE));
        di = 1.0f / sqrtf(deg);
        dinv[i] = di;
        // per-copy exclusive offsets (u16 x 8)
        unsigned o01 = 0, o23, o45, o67;
        unsigned run = (unsigned)cnts[0];
        o01 = run << 16;                 run += cnts[1];
        o23 = run | ((run + cnts[2]) << 16); run += cnts[2] + cnts[3];
        o45 = run | ((run + cnts[4]) << 16); run += cnts[4] + cnts[5];
        o67 = run | ((run + cnts[6]) << 16);
        coffs[i] = make_uint4(o01, o23, o45, o67);
        rowlen = v_edges + 1;            // +1 self-loop
    }
    int s = rowlen;
    #pragma unroll
    for (int off = 1; off < 64; off <<= 1) {
        int u = __shfl_up(s, off, 64);
        if (lane >= off) s += u;
    }
    if (lane == 63) wtot[wv] = s;
    __syncthreads();

    int btot = 0;
    #pragma unroll
    for (int j = 0; j < 16; ++j) btot += wtot[j];
    if (tid == 0) {
        bsum[bid] = btot;
        __hip_atomic_store(&bflag[bid], 1, __ATOMIC_RELEASE, __HIP_MEMORY_SCOPE_AGENT);
    }
    if (tid < 64) {
        int acc = 0;
        if (tid < bid) {
            while (__hip_atomic_load(&bflag[tid], __ATOMIC_ACQUIRE,
                                     __HIP_MEMORY_SCOPE_AGENT) == 0) {}
            acc = bsum[tid];
        }
        #pragma unroll
        for (int off = 32; off >= 1; off >>= 1) acc += __shfl_xor(acc, off, 64);
        if (tid == 0) sbase_sh = acc;
    }
    __syncthreads();
    int base = sbase_sh;

    int wpre = 0;
    for (int j = 0; j < wv; ++j) wpre += wtot[j];
    if (i < n) {
        int r = base + wpre + (s - rowlen);       // global exclusive prefix
        rowptr[i] = r;
        ent[r + v_edges] = make_uint2((unsigned)i, __float_as_uint(di * di));  // self-loop
    }
    if (bid == NB - 1 && tid == 0) rowptr[n] = base + btot;
}

// atomic-free scatter: pos = rowptr[d] + copy_offset + local_rank
__global__ void k_fill(const int* __restrict__ src, const int* __restrict__ dst,
                       const float* __restrict__ w, const float* __restrict__ dinv,
                       const int* __restrict__ rowptr, const unsigned* __restrict__ rank,
                       const uint4* __restrict__ coffs, uint2* __restrict__ ent, int e) {
    int i = blockIdx.x * blockDim.x + threadIdx.x;
    if (i >= e) return;
    int s = src[i], d = dst[i];
    unsigned rk = rank[i];
    int c = rk & 7, lr = (int)(rk >> 3);
    uint4 cf = coffs[d];
    unsigned word = ((const unsigned*)&cf)[c >> 1];
    int off = (c & 1) ? (int)(word >> 16) : (int)(word & 0xFFFFu);
    int pos = rowptr[d] + off + lr;
    float v = dinv[s] * w[i] * dinv[d];
    ent[pos] = make_uint2((unsigned)s, __float_as_uint(v));
}

// ---------------- dense transform: bf16 MFMA GEMM (bf16 in) ----------------

__global__ __launch_bounds__(256) void k_gemm_bf(const unsigned short* __restrict__ A,
        const unsigned short* __restrict__ Wt, unsigned short* __restrict__ out, int n) {
    int tid = threadIdx.x;
    int wave = tid >> 6, lane = tid & 63;
    int quad = lane >> 4, c16 = lane & 15;
    int rowbase = blockIdx.x * 64 + wave * 16;
    int rowA = rowbase + c16;
    if (rowA >= n) rowA = n - 1;
    f4v acc[8];
    #pragma unroll
    for (int t = 0; t < 8; ++t) acc[t] = (f4v){0.f, 0.f, 0.f, 0.f};
    #pragma unroll
    for (int k0 = 0; k0 < 128; k0 += 32) {
        s8v a = *(const s8v*)(A + (size_t)rowA * FD + k0 + quad * 8);
        #pragma unroll
        for (int t = 0; t < 8; ++t) {
            s8v b = *(const s8v*)(Wt + (size_t)(t * 16 + c16) * FD + k0 + quad * 8);
            acc[t] = __builtin_amdgcn_mfma_f32_16x16x32_bf16(a, b, acc[t], 0, 0, 0);
        }
    }
    #pragma unroll
    for (int t = 0; t < 8; ++t) {
        #pragma unroll
        for (int r = 0; r < 4; ++r) {
            int row = rowbase + quad * 4 + r;
            if (row < n) out[(size_t)row * FD + t * 16 + c16] = f2b(acc[t][r]);
        }
    }
}

// ---------------- sparse aggregation, bf16 features ----------------
// one wave per node; 16 edges in flight per iter
__global__ __launch_bounds__(256) void k_spmm_bf(const int* __restrict__ rowptr,
        const uint2* __restrict__ ent, const unsigned short* __restrict__ tin,
        const float* __restrict__ bias, unsigned short* __restrict__ out,
        int n, int dorelu) {
    int w = (blockIdx.x * blockDim.x + threadIdx.x) >> 6;
    int lane = threadIdx.x & 63;
    if (w >= n) return;
    int c = lane & 15, g = lane >> 4;
    int beg = rowptr[w], end = rowptr[w + 1];
    float acc[8];
    #pragma unroll
    for (int j = 0; j < 8; ++j) acc[j] = 0.0f;
    for (int e0 = beg; e0 < end; e0 += 16) {
        uint2 en[4];
        uint4 t[4];
        #pragma unroll
        for (int u = 0; u < 4; ++u) {
            int e = e0 + 4 * u + g;
            en[u] = (e < end) ? ent[e] : make_uint2(0u, 0u);
        }
        #pragma unroll
        for (int u = 0; u < 4; ++u)
            t[u] = *(const uint4*)(tin + (size_t)en[u].x * FD + c * 8);
        #pragma unroll
        for (int u = 0; u < 4; ++u) {
            float v = __uint_as_float(en[u].y);
            acc[0] += v * __uint_as_float(t[u].x << 16);
            acc[1] += v * __uint_as_float(t[u].x & 0xFFFF0000u);
            acc[2] += v * __uint_as_float(t[u].y << 16);
            acc[3] += v * __uint_as_float(t[u].y & 0xFFFF0000u);
            acc[4] += v * __uint_as_float(t[u].z << 16);
            acc[5] += v * __uint_as_float(t[u].z & 0xFFFF0000u);
            acc[6] += v * __uint_as_float(t[u].w << 16);
            acc[7] += v * __uint_as_float(t[u].w & 0xFFFF0000u);
        }
    }
    #pragma unroll
    for (int j = 0; j < 8; ++j) {
        acc[j] += __shfl_xor(acc[j], 16, 64);
        acc[j] += __shfl_xor(acc[j], 32, 64);
    }
    if (g == 0) {
        uint4 r;
        float o[8];
        #pragma unroll
        for (int j = 0; j < 8; ++j) {
            float x = acc[j] + bias[c * 8 + j];
            o[j] = dorelu ? fmaxf(x, 0.0f) : x;
        }
        r.x = (unsigned)f2b(o[0]) | ((unsigned)f2b(o[1]) << 16);
        r.y = (unsigned)f2b(o[2]) | ((unsigned)f2b(o[3]) << 16);
        r.z = (unsigned)f2b(o[4]) | ((unsigned)f2b(o[5]) << 16);
        r.w = (unsigned)f2b(o[6]) | ((unsigned)f2b(o[7]) << 16);
        *(uint4*)(out + (size_t)w * FD + c * 8) = r;
    }
}

// layer-2 aggregation + relu + fused h2@W3 epilogue -> 10 f32/node (no hB write)
__global__ __launch_bounds__(256) void k_spmm_w3(const int* __restrict__ rowptr,
        const uint2* __restrict__ ent, const unsigned short* __restrict__ tin,
        const float* __restrict__ bias2, const float* __restrict__ W3,
        float* __restrict__ outc, int n) {
    int w = (blockIdx.x * blockDim.x + threadIdx.x) >> 6;
    int lane = threadIdx.x & 63;
    if (w >= n) return;
    int c = lane & 15, g = lane >> 4;
    int beg = rowptr[w], end = rowptr[w + 1];
    float acc[8];
    #pragma unroll
    for (int j = 0; j < 8; ++j) acc[j] = 0.0f;
    for (int e0 = beg; e0 < end; e0 += 16) {
        uint2 en[4];
        uint4 t[4];
        #pragma unroll
        for (int u = 0; u < 4; ++u) {
            int e = e0 + 4 * u + g;
            en[u] = (e < end) ? ent[e] : make_uint2(0u, 0u);
        }
        #pragma unroll
        for (int u = 0; u < 4; ++u)
            t[u] = *(const uint4*)(tin + (size_t)en[u].x * FD + c * 8);
        #pragma unroll
        for (int u = 0; u < 4; ++u) {
            float v = __uint_as_float(en[u].y);
            acc[0] += v * __uint_as_float(t[u].x << 16);
            acc[1] += v * __uint_as_float(t[u].x & 0xFFFF0000u);
            acc[2] += v * __uint_as_float(t[u].y << 16);
            acc[3] += v * __uint_as_float(t[u].y & 0xFFFF0000u);
            acc[4] += v * __uint_as_float(t[u].z << 16);
            acc[5] += v * __uint_as_float(t[u].z & 0xFFFF0000u);
            acc[6] += v * __uint_as_float(t[u].w << 16);
            acc[7] += v * __uint_as_float(t[u].w & 0xFFFF0000u);
        }
    }
    #pragma unroll
    for (int j = 0; j < 8; ++j) {
        acc[j] += __shfl_xor(acc[j], 16, 64);
        acc[j] += __shfl_xor(acc[j], 32, 64);
    }
    if (g == 0) {
        // h2 row: lane c holds cols [c*8, c*8+8) in o[]
        float o[8];
        #pragma unroll
        for (int j = 0; j < 8; ++j)
            o[j] = fmaxf(acc[j] + bias2[c * 8 + j], 0.0f);
        // partial of h2 @ W3: lane c uses W3 rows [c*8, c*8+8) = contiguous chunk
        float p10[OUTD];
        #pragma unroll
        for (int cc = 0; cc < OUTD; ++cc) p10[cc] = 0.0f;
        const float* w3c = W3 + c * 8 * OUTD;
        #pragma unroll
        for (int j = 0; j < 8; ++j) {
            float hv = o[j];
            #pragma unroll
            for (int cc = 0; cc < OUTD; ++cc)
                p10[cc] += hv * w3c[j * OUTD + cc];
        }
        // reduce across the 16 lanes of group 0
        #pragma unroll
        for (int off = 8; off >= 1; off >>= 1)
            #pragma unroll
            for (int cc = 0; cc < OUTD; ++cc)
                p10[cc] += __shfl_xor(p10[cc], off, 64);
        if (c == 0) {
            float* op = outc + (size_t)w * OUTD;
            #pragma unroll
            for (int cc = 0; cc < OUTD; ++cc) op[cc] = p10[cc];
        }
    }
}

// one thread per (node, feature), 10 features, f32 (input 2 MB -> L2-resident)
__global__ void k_spmm10(const int* __restrict__ rowptr, const uint2* __restrict__ ent,
        const float* __restrict__ tin, const float* __restrict__ bias,
        float* __restrict__ out, int n) {
    int t = blockIdx.x * blockDim.x + threadIdx.x;
    int node = t / OUTD;
    int c = t - node * OUTD;
    if (node >= n) return;
    int beg = rowptr[node], end = rowptr[node + 1];
    float acc = 0.0f;
    for (int e = beg; e < end; ++e) {
        uint2 en = ent[e];
        acc += __uint_as_float(en.y) * tin[(size_t)en.x * OUTD + c];
    }
    out[(size_t)node * OUTD + c] = acc + bias[c];
}

// ---------------- pooling + log_softmax (1 block/graph) ----------------

__global__ __launch_bounds__(256) void k_poolfin(const float* __restrict__ h,
        const int* __restrict__ gstart, float* __restrict__ out) {
    int g = blockIdx.x;
    int beg = gstart[g], end = gstart[g + 1];
    int tid = threadIdx.x;
    int lane = tid & 63, wv = tid >> 6;
    float acc[OUTD];
    #pragma unroll
    for (int c = 0; c < OUTD; ++c) acc[c] = 0.0f;
    for (int i = beg + tid; i < end; i += 256) {
        const float* hp = h + (size_t)i * OUTD;
        #pragma unroll
        for (int c = 0; c < OUTD; ++c) acc[c] += hp[c];
    }
    #pragma unroll
    for (int off = 32; off >= 1; off >>= 1)
        #pragma unroll
        for (int c = 0; c < OUTD; ++c) acc[c] += __shfl_down(acc[c], off, 64);
    __shared__ float ws[4][OUTD];
    if (lane == 0)
        #pragma unroll
        for (int c = 0; c < OUTD; ++c) ws[wv][c] = acc[c];
    __syncthreads();
    if (tid == 0) {
        float cf = fmaxf((float)(end - beg), 1.0f);
        float v[OUTD], m = -1e30f;
        #pragma unroll
        for (int c = 0; c < OUTD; ++c) {
            v[c] = (ws[0][c] + ws[1][c] + ws[2][c] + ws[3][c]) / cf;
            m = fmaxf(m, v[c]);
        }
        float s = 0.0f;
        #pragma unroll
        for (int c = 0; c < OUTD; ++c) s += expf(v[c] - m);
        float l = logf(s);
        #pragma unroll
        for (int c = 0; c < OUTD; ++c) out[g * OUTD + c] = v[c] - m - l;
    }
}

// ---------------- launcher ----------------

extern "C" void kernel_launch(void* const* d_in, const int* in_sizes, int n_in,
                              void* d_out, int out_size, void* d_ws, size_t ws_size,
                              hipStream_t stream) {
    const float* x   = (const float*)d_in[0];
    const int*   ei  = (const int*)d_in[1];
    const float* ew  = (const float*)d_in[2];
    const int*   bat = (const int*)d_in[3];
    const float* W1  = (const float*)d_in[4];
    const float* b1  = (const float*)d_in[5];
    const float* W2  = (const float*)d_in[6];
    const float* b2  = (const float*)d_in[7];
    const float* W3  = (const float*)d_in[8];
    const float* b3  = (const float*)d_in[9];
    float* out = (float*)d_out;

    const int* src = ei;
    const int* dst = ei + EE;

    char* p = (char*)d_ws;
    auto alloc = [&](size_t bytes) -> void* {
        void* r = (void*)p;
        p += (bytes + 255) & ~(size_t)255;
        return r;
    };
    unsigned long long* packed = (unsigned long long*)alloc((size_t)NP * NN * 8);
    float*          dinv   = (float*)alloc((size_t)NN * 4);
    int*            rowptr = (int*)  alloc((size_t)(NN + 1) * 4);
    unsigned*       rank   = (unsigned*)alloc((size_t)EE * 4);
    uint4*          coffs  = (uint4*)alloc((size_t)NN * 16);
    uint2*          ent    = (uint2*)alloc((size_t)(EE + NN) * 8);
    unsigned short* Wt1    = (unsigned short*)alloc((size_t)FD * FD * 2);
    unsigned short* Wt2    = (unsigned short*)alloc((size_t)FD * FD * 2);
    unsigned short* hA     = (unsigned short*)alloc((size_t)NN * FD * 2);
    unsigned short* hB     = (unsigned short*)alloc((size_t)NN * FD * 2);
    float*          bufC   = (float*)alloc((size_t)NN * OUTD * 4);
    float*          bufD   = (float*)alloc((size_t)NN * OUTD * 4);
    int*            bsum   = (int*)  alloc((size_t)NB * 4);
    int*            bflag  = (int*)  alloc((size_t)NB * 4);
    int*            gstart = (int*)  alloc((size_t)(GG + 1) * 4);
    (void)ws_size; (void)in_sizes; (void)n_in; (void)out_size;

    const int B = 256;
    // prep (zeroes scan flags + 8 partials -- workspace is poisoned each call)
    k_prep <<<(NN + B - 1) / B, B, 0, stream>>>(packed, W1, W2, Wt1, Wt2, bflag, NN);
    // fused: layer-1 GEMM || 8-way degree atomics+rank || graph bounds
    k_mega1<<<GB + DB + BB, B, 0, stream>>>(x, Wt1, hA, dst, ew, packed, rank, bat, gstart);
    // single-kernel scan: merge partials, dinv, per-copy offsets, self-loop entries
    k_scan <<<NB, 1024, 0, stream>>>(packed, rowptr, dinv, ent, coffs, bsum, bflag, NN);
    // CSR fill (atomic-free)
    k_fill <<<(EE + B - 1) / B, B, 0, stream>>>(src, dst, ew, dinv, rowptr, rank, coffs, ent, EE);

    // layer 1 aggregation
    k_spmm_bf<<<(NN * 64 + B - 1) / B, B, 0, stream>>>(rowptr, ent, hA, b1, hB, NN, 1);
    // layer 2 transform
    k_gemm_bf<<<GB, B, 0, stream>>>(hB, Wt2, hA, NN);
    // layer 2 aggregation + relu + fused W3 transform -> bufC [NN x 10]
    k_spmm_w3<<<(NN * 64 + B - 1) / B, B, 0, stream>>>(rowptr, ent, hA, b2, W3, bufC, NN);
    // layer 3 aggregation
    k_spmm10 <<<(NN * OUTD + B - 1) / B, B, 0, stream>>>(rowptr, ent, bufC, b3, bufD, NN);
    // pool + log_softmax
    k_poolfin<<<GG, 256, 0, stream>>>(bufD, gstart, out);
}

// Round 9
// 281.782 us; speedup vs baseline: 1.1557x; 1.1557x over previous
//
#include <hip/hip_runtime.h>
#include <math.h>

#define NN 50000
#define EE 800000
#define GG 64
#define FD 128
#define OUTD 10
#define NB 49           // ceil(NN/1024) scan blocks
#define GB 782          // (NN+63)/64 gemm blocks
#define BB 196          // (NN+255)/256 bounds blocks
#define NBU 196         // buckets of 256 nodes: ceil(50000/256)
#define NBK 128         // edge-chunk blocks
#define CH 6250         // edges per chunk (128*6250 = 800000 exactly)

typedef __attribute__((ext_vector_type(8))) short s8v;    // 8 bf16
typedef __attribute__((ext_vector_type(4))) float f4v;    // 4 f32 acc

static __device__ inline unsigned short f2b(float f) {    // f32 -> bf16 RNE
    unsigned int u = __float_as_uint(f);
    return (unsigned short)((u + 0x7FFFu + ((u >> 16) & 1u)) >> 16);
}

// ---------------- prep: zero scan flags, transpose weights ----------------

__global__ void k_prep(const float* __restrict__ W1, const float* __restrict__ W2,
                       unsigned short* __restrict__ Wt1, unsigned short* __restrict__ Wt2,
                       int* __restrict__ bflag) {
    int i = blockIdx.x * blockDim.x + threadIdx.x;
    if (i < FD * FD) {
        int nn = i >> 7, k = i & 127;
        Wt1[i] = f2b(W1[k * FD + nn]);
        Wt2[i] = f2b(W2[k * FD + nn]);
    }
    if (i < NB) bflag[i] = 0;    // workspace poisoned 0xAA -> must zero
}

// ---------------- mega kernel: gemm1 || bucket-histogram || bounds ----------------

static __device__ inline void gemm_f32in_body(int bid, const float* __restrict__ A,
        const unsigned short* __restrict__ Wt, unsigned short* __restrict__ out, int n) {
    int tid = threadIdx.x;
    int wave = tid >> 6, lane = tid & 63;
    int quad = lane >> 4, c16 = lane & 15;
    int rowbase = bid * 64 + wave * 16;
    int rowA = rowbase + c16;
    if (rowA >= n) rowA = n - 1;
    f4v acc[8];
    #pragma unroll
    for (int t = 0; t < 8; ++t) acc[t] = (f4v){0.f, 0.f, 0.f, 0.f};
    #pragma unroll
    for (int k0 = 0; k0 < 128; k0 += 32) {
        const float* ap = A + (size_t)rowA * FD + k0 + quad * 8;
        float4 a0 = *(const float4*)ap;
        float4 a1 = *(const float4*)(ap + 4);
        s8v a;
        a[0] = (short)f2b(a0.x); a[1] = (short)f2b(a0.y);
        a[2] = (short)f2b(a0.z); a[3] = (short)f2b(a0.w);
        a[4] = (short)f2b(a1.x); a[5] = (short)f2b(a1.y);
        a[6] = (short)f2b(a1.z); a[7] = (short)f2b(a1.w);
        #pragma unroll
        for (int t = 0; t < 8; ++t) {
            s8v b = *(const s8v*)(Wt + (size_t)(t * 16 + c16) * FD + k0 + quad * 8);
            acc[t] = __builtin_amdgcn_mfma_f32_16x16x32_bf16(a, b, acc[t], 0, 0, 0);
        }
    }
    #pragma unroll
    for (int t = 0; t < 8; ++t) {
        #pragma unroll
        for (int r = 0; r < 4; ++r) {
            int row = rowbase + quad * 4 + r;
            if (row < n) out[(size_t)row * FD + t * 16 + c16] = f2b(acc[t][r]);
        }
    }
}

__global__ __launch_bounds__(256) void k_megaA(const float* __restrict__ x,
        const unsigned short* __restrict__ Wt1, unsigned short* __restrict__ hA,
        const int* __restrict__ dst, int* __restrict__ cnt2d,
        const int* __restrict__ batch, int* __restrict__ gstart) {
    int b = blockIdx.x;
    int tid = threadIdx.x;
    if (b < GB) {
        gemm_f32in_body(b, x, Wt1, hA, NN);
    } else if (b < GB + NBK) {
        // per-chunk bucket histogram (LDS), plain stores of per-block counts
        __shared__ unsigned hist[NBU];
        int blk = b - GB;
        if (tid < NBU) hist[tid] = 0;
        __syncthreads();
        int e0 = blk * CH;
        for (int e = e0 + tid; e < e0 + CH; e += 256)
            atomicAdd(&hist[(unsigned)dst[e] >> 8], 1u);
        __syncthreads();
        if (tid < NBU) cnt2d[blk * NBU + tid] = (int)hist[tid];
    } else {
        int i = (b - GB - NBK) * 256 + tid;
        if (i < NN) {
            int bb = batch[i];
            int bp = (i == 0) ? -1 : batch[i - 1];
            for (int g = bp + 1; g <= bb; ++g) gstart[g] = i;
            if (i == NN - 1)
                for (int g = bb + 1; g <= GG; ++g) gstart[g] = NN;
        }
    }
}

// ---------------- bucket scan: per-block offsets + bucket bases (1 block) ----------------

__global__ __launch_bounds__(256) void k_bscan(int* __restrict__ cnt2d,  // becomes off2d
        int* __restrict__ bucketbase) {
    __shared__ int colsum[NBU];
    int tid = threadIdx.x;
    if (tid < NBU) {
        int run = 0;
        for (int blk = 0; blk < NBK; ++blk) {
            int idx = blk * NBU + tid;
            int t = cnt2d[idx];
            cnt2d[idx] = run;          // per-block exclusive offset within bucket
            run += t;
        }
        colsum[tid] = run;             // total edges in bucket
    }
    __syncthreads();
    if (tid == 0) {
        int run = 0;
        for (int b = 0; b < NBU; ++b) {
            bucketbase[b] = run;
            run += colsum[b];
        }
        bucketbase[NBU] = run;         // == EE
    }
}

// ---------------- scatter edges into bucket-segmented records ----------------
// rec[slot] = ( (d&255)<<16 | src , bits(w) );  no global atomics (LDS cursors)

__global__ __launch_bounds__(256) void k_scatter(const int* __restrict__ src,
        const int* __restrict__ dst, const float* __restrict__ ew,
        const int* __restrict__ off2d, const int* __restrict__ bucketbase,
        uint2* __restrict__ rec) {
    __shared__ unsigned cur[NBU];
    int tid = threadIdx.x;
    int blk = blockIdx.x;
    if (tid < NBU) cur[tid] = (unsigned)(bucketbase[tid] + off2d[blk * NBU + tid]);
    __syncthreads();
    int e0 = blk * CH;
    for (int e = e0 + tid; e < e0 + CH; e += 256) {
        int d = dst[e];
        unsigned bkt = (unsigned)d >> 8;
        unsigned pos = atomicAdd(&cur[bkt], 1u);
        rec[pos] = make_uint2(((unsigned)(d & 255) << 16) | (unsigned)src[e],
                              __float_as_uint(ew[e]));
    }
}

// ---------------- per-bucket rank + per-node count + weighted degree (LDS only) ----------------

__global__ __launch_bounds__(1024) void k_rank(const uint2* __restrict__ rec,
        const int* __restrict__ bucketbase, unsigned short* __restrict__ rankb,
        int* __restrict__ cnt_g, float* __restrict__ wdeg_g) {
    __shared__ unsigned cntS[256];
    __shared__ float wdegS[256];
    int b = blockIdx.x;
    int tid = threadIdx.x;
    if (tid < 256) { cntS[tid] = 0; wdegS[tid] = 0.0f; }
    __syncthreads();
    int beg = bucketbase[b], end = bucketbase[b + 1];
    for (int s = beg + tid; s < end; s += 1024) {
        uint2 r = rec[s];
        unsigned dl = r.x >> 16;
        unsigned old = atomicAdd(&cntS[dl], 1u);
        rankb[s] = (unsigned short)old;
        atomicAdd(&wdegS[dl], __uint_as_float(r.y));
    }
    __syncthreads();
    if (tid < 256) {
        int node = b * 256 + tid;
        if (node < NN) {
            cnt_g[node] = (int)cntS[tid];
            wdeg_g[node] = wdegS[tid];
        }
    }
}

// ---------------- single-kernel scan (decoupled lookback) ----------------
// rowptr from cnt+1; dinv = rsqrt(wdeg+1); writes self-loop entry

__global__ __launch_bounds__(1024) void k_scan(const int* __restrict__ cnt_g,
        const float* __restrict__ wdeg_g, int* __restrict__ rowptr,
        float* __restrict__ dinv, uint2* __restrict__ ent,
        int* __restrict__ bsum, int* __restrict__ bflag, int n) {
    __shared__ int wtot[16];
    __shared__ int sbase_sh;
    int tid = threadIdx.x;
    int bid = blockIdx.x;
    int i = bid * 1024 + tid;
    int lane = tid & 63, wv = tid >> 6;

    int v_edges = 0, rowlen = 0;
    float di = 0.0f;
    if (i < n) {
        v_edges = cnt_g[i];
        float deg = wdeg_g[i] + 1.0f;          // +1 self-loop weight
        di = 1.0f / sqrtf(deg);
        dinv[i] = di;
        rowlen = v_edges + 1;                  // +1 self-loop entry
    }
    int s = rowlen;
    #pragma unroll
    for (int off = 1; off < 64; off <<= 1) {
        int u = __shfl_up(s, off, 64);
        if (lane >= off) s += u;
    }
    if (lane == 63) wtot[wv] = s;
    __syncthreads();

    int btot = 0;
    #pragma unroll
    for (int j = 0; j < 16; ++j) btot += wtot[j];
    if (tid == 0) {
        bsum[bid] = btot;
        __hip_atomic_store(&bflag[bid], 1, __ATOMIC_RELEASE, __HIP_MEMORY_SCOPE_AGENT);
    }
    if (tid < 64) {
        int acc = 0;
        if (tid < bid) {
            while (__hip_atomic_load(&bflag[tid], __ATOMIC_ACQUIRE,
                                     __HIP_MEMORY_SCOPE_AGENT) == 0) {}
            acc = bsum[tid];
        }
        #pragma unroll
        for (int off = 32; off >= 1; off >>= 1) acc += __shfl_xor(acc, off, 64);
        if (tid == 0) sbase_sh = acc;
    }
    __syncthreads();
    int base = sbase_sh;

    int wpre = 0;
    for (int j = 0; j < wv; ++j) wpre += wtot[j];
    if (i < n) {
        int r = base + wpre + (s - rowlen);
        rowptr[i] = r;
        ent[r + v_edges] = make_uint2((unsigned)i, __float_as_uint(di * di));  // self-loop
    }
    if (bid == NB - 1 && tid == 0) rowptr[n] = base + btot;
}

// ---------------- final CSR fill: coalesced reads, bucket-localized ent writes ----------------

__global__ __launch_bounds__(1024) void k_fill2(const uint2* __restrict__ rec,
        const unsigned short* __restrict__ rankb, const int* __restrict__ bucketbase,
        const int* __restrict__ rowptr, const float* __restrict__ dinv,
        uint2* __restrict__ ent) {
    int b = blockIdx.x;
    int tid = threadIdx.x;
    int beg = bucketbase[b], end = bucketbase[b + 1];
    for (int s = beg + tid; s < end; s += 1024) {
        uint2 r = rec[s];
        unsigned sn = r.x & 0xFFFFu;
        int d = (b << 8) | (int)(r.x >> 16);
        int pos = rowptr[d] + (int)rankb[s];
        float val = dinv[sn] * __uint_as_float(r.y) * dinv[d];
        ent[pos] = make_uint2(sn, __float_as_uint(val));
    }
}

// ---------------- dense transform: bf16 MFMA GEMM (bf16 in) ----------------

__global__ __launch_bounds__(256) void k_gemm_bf(const unsigned short* __restrict__ A,
        const unsigned short* __restrict__ Wt, unsigned short* __restrict__ out, int n) {
    int tid = threadIdx.x;
    int wave = tid >> 6, lane = tid & 63;
    int quad = lane >> 4, c16 = lane & 15;
    int rowbase = blockIdx.x * 64 + wave * 16;
    int rowA = rowbase + c16;
    if (rowA >= n) rowA = n - 1;
    f4v acc[8];
    #pragma unroll
    for (int t = 0; t < 8; ++t) acc[t] = (f4v){0.f, 0.f, 0.f, 0.f};
    #pragma unroll
    for (int k0 = 0; k0 < 128; k0 += 32) {
        s8v a = *(const s8v*)(A + (size_t)rowA * FD + k0 + quad * 8);
        #pragma unroll
        for (int t = 0; t < 8; ++t) {
            s8v b = *(const s8v*)(Wt + (size_t)(t * 16 + c16) * FD + k0 + quad * 8);
            acc[t] = __builtin_amdgcn_mfma_f32_16x16x32_bf16(a, b, acc[t], 0, 0, 0);
        }
    }
    #pragma unroll
    for (int t = 0; t < 8; ++t) {
        #pragma unroll
        for (int r = 0; r < 4; ++r) {
            int row = rowbase + quad * 4 + r;
            if (row < n) out[(size_t)row * FD + t * 16 + c16] = f2b(acc[t][r]);
        }
    }
}

// out[n][10] = A[n][128] @ W[128][10], A bf16, W f32 (LDS), out f32
__global__ void k_gemm10(const unsigned short* __restrict__ A, const float* __restrict__ W,
                         float* __restrict__ out, int n) {
    __shared__ float Ws[FD * OUTD];
    int tid = threadIdx.x;
    for (int i = tid; i < FD * OUTD; i += blockDim.x) Ws[i] = W[i];
    __syncthreads();
    int i = blockIdx.x * blockDim.x + tid;
    if (i >= n) return;
    float acc[OUTD];
    #pragma unroll
    for (int c = 0; c < OUTD; ++c) acc[c] = 0.0f;
    const unsigned short* a = A + (size_t)i * FD;
    for (int k0 = 0; k0 < FD; k0 += 8) {
        uint4 t = *(const uint4*)(a + k0);
        float av[8];
        av[0] = __uint_as_float(t.x << 16); av[1] = __uint_as_float(t.x & 0xFFFF0000u);
        av[2] = __uint_as_float(t.y << 16); av[3] = __uint_as_float(t.y & 0xFFFF0000u);
        av[4] = __uint_as_float(t.z << 16); av[5] = __uint_as_float(t.z & 0xFFFF0000u);
        av[6] = __uint_as_float(t.w << 16); av[7] = __uint_as_float(t.w & 0xFFFF0000u);
        #pragma unroll
        for (int j = 0; j < 8; ++j)
            #pragma unroll
            for (int c = 0; c < OUTD; ++c) acc[c] += av[j] * Ws[(k0 + j) * OUTD + c];
    }
    float* o = out + (size_t)i * OUTD;
    #pragma unroll
    for (int c = 0; c < OUTD; ++c) o[c] = acc[c];
}

// ---------------- sparse aggregation, bf16 features ----------------
// one wave per node; 16 edges in flight per iter
__global__ __launch_bounds__(256) void k_spmm_bf(const int* __restrict__ rowptr,
        const uint2* __restrict__ ent, const unsigned short* __restrict__ tin,
        const float* __restrict__ bias, unsigned short* __restrict__ out,
        int n, int dorelu) {
    int w = (blockIdx.x * blockDim.x + threadIdx.x) >> 6;
    int lane = threadIdx.x & 63;
    if (w >= n) return;
    int c = lane & 15, g = lane >> 4;
    int beg = rowptr[w], end = rowptr[w + 1];
    float acc[8];
    #pragma unroll
    for (int j = 0; j < 8; ++j) acc[j] = 0.0f;
    for (int e0 = beg; e0 < end; e0 += 16) {
        uint2 en[4];
        uint4 t[4];
        #pragma unroll
        for (int u = 0; u < 4; ++u) {
            int e = e0 + 4 * u + g;
            en[u] = (e < end) ? ent[e] : make_uint2(0u, 0u);
        }
        #pragma unroll
        for (int u = 0; u < 4; ++u)
            t[u] = *(const uint4*)(tin + (size_t)en[u].x * FD + c * 8);
        #pragma unroll
        for (int u = 0; u < 4; ++u) {
            float v = __uint_as_float(en[u].y);
            acc[0] += v * __uint_as_float(t[u].x << 16);
            acc[1] += v * __uint_as_float(t[u].x & 0xFFFF0000u);
            acc[2] += v * __uint_as_float(t[u].y << 16);
            acc[3] += v * __uint_as_float(t[u].y & 0xFFFF0000u);
            acc[4] += v * __uint_as_float(t[u].z << 16);
            acc[5] += v * __uint_as_float(t[u].z & 0xFFFF0000u);
            acc[6] += v * __uint_as_float(t[u].w << 16);
            acc[7] += v * __uint_as_float(t[u].w & 0xFFFF0000u);
        }
    }
    #pragma unroll
    for (int j = 0; j < 8; ++j) {
        acc[j] += __shfl_xor(acc[j], 16, 64);
        acc[j] += __shfl_xor(acc[j], 32, 64);
    }
    if (g == 0) {
        uint4 r;
        float o[8];
        #pragma unroll
        for (int j = 0; j < 8; ++j) {
            float x = acc[j] + bias[c * 8 + j];
            o[j] = dorelu ? fmaxf(x, 0.0f) : x;
        }
        r.x = (unsigned)f2b(o[0]) | ((unsigned)f2b(o[1]) << 16);
        r.y = (unsigned)f2b(o[2]) | ((unsigned)f2b(o[3]) << 16);
        r.z = (unsigned)f2b(o[4]) | ((unsigned)f2b(o[5]) << 16);
        r.w = (unsigned)f2b(o[6]) | ((unsigned)f2b(o[7]) << 16);
        *(uint4*)(out + (size_t)w * FD + c * 8) = r;
    }
}

// one thread per (node, feature), 10 features, f32 (input 2 MB -> cache-resident)
__global__ void k_spmm10(const int* __restrict__ rowptr, const uint2* __restrict__ ent,
        const float* __restrict__ tin, const float* __restrict__ bias,
        float* __restrict__ out, int n) {
    int t = blockIdx.x * blockDim.x + threadIdx.x;
    int node = t / OUTD;
    int c = t - node * OUTD;
    if (node >= n) return;
    int beg = rowptr[node], end = rowptr[node + 1];
    float acc = 0.0f;
    for (int e = beg; e < end; ++e) {
        uint2 en = ent[e];
        acc += __uint_as_float(en.y) * tin[(size_t)en.x * OUTD + c];
    }
    out[(size_t)node * OUTD + c] = acc + bias[c];
}

// ---------------- pooling + log_softmax (1 block/graph) ----------------

__global__ __launch_bounds__(256) void k_poolfin(const float* __restrict__ h,
        const int* __restrict__ gstart, float* __restrict__ out) {
    int g = blockIdx.x;
    int beg = gstart[g], end = gstart[g + 1];
    int tid = threadIdx.x;
    int lane = tid & 63, wv = tid >> 6;
    float acc[OUTD];
    #pragma unroll
    for (int c = 0; c < OUTD; ++c) acc[c] = 0.0f;
    for (int i = beg + tid; i < end; i += 256) {
        const float* hp = h + (size_t)i * OUTD;
        #pragma unroll
        for (int c = 0; c < OUTD; ++c) acc[c] += hp[c];
    }
    #pragma unroll
    for (int off = 32; off >= 1; off >>= 1)
        #pragma unroll
        for (int c = 0; c < OUTD; ++c) acc[c] += __shfl_down(acc[c], off, 64);
    __shared__ float ws[4][OUTD];
    if (lane == 0)
        #pragma unroll
        for (int c = 0; c < OUTD; ++c) ws[wv][c] = acc[c];
    __syncthreads();
    if (tid == 0) {
        float cf = fmaxf((float)(end - beg), 1.0f);
        float v[OUTD], m = -1e30f;
        #pragma unroll
        for (int c = 0; c < OUTD; ++c) {
            v[c] = (ws[0][c] + ws[1][c] + ws[2][c] + ws[3][c]) / cf;
            m = fmaxf(m, v[c]);
        }
        float s = 0.0f;
        #pragma unroll
        for (int c = 0; c < OUTD; ++c) s += expf(v[c] - m);
        float l = logf(s);
        #pragma unroll
        for (int c = 0; c < OUTD; ++c) out[g * OUTD + c] = v[c] - m - l;
    }
}

// ---------------- launcher ----------------

extern "C" void kernel_launch(void* const* d_in, const int* in_sizes, int n_in,
                              void* d_out, int out_size, void* d_ws, size_t ws_size,
                              hipStream_t stream) {
    const float* x   = (const float*)d_in[0];
    const int*   ei  = (const int*)d_in[1];
    const float* ew  = (const float*)d_in[2];
    const int*   bat = (const int*)d_in[3];
    const float* W1  = (const float*)d_in[4];
    const float* b1  = (const float*)d_in[5];
    const float* W2  = (const float*)d_in[6];
    const float* b2  = (const float*)d_in[7];
    const float* W3  = (const float*)d_in[8];
    const float* b3  = (const float*)d_in[9];
    float* out = (float*)d_out;

    const int* src = ei;
    const int* dst = ei + EE;

    char* p = (char*)d_ws;
    auto alloc = [&](size_t bytes) -> void* {
        void* r = (void*)p;
        p += (bytes + 255) & ~(size_t)255;
        return r;
    };
    int*            cnt2d  = (int*)  alloc((size_t)NBK * NBU * 4);   // -> off2d in place
    int*            bbase  = (int*)  alloc((size_t)(NBU + 1) * 4);
    uint2*          rec    = (uint2*)alloc((size_t)EE * 8);
    unsigned short* rankb  = (unsigned short*)alloc((size_t)EE * 2);
    int*            cnt_g  = (int*)  alloc((size_t)NN * 4);
    float*          wdeg_g = (float*)alloc((size_t)NN * 4);
    float*          dinv   = (float*)alloc((size_t)NN * 4);
    int*            rowptr = (int*)  alloc((size_t)(NN + 1) * 4);
    uint2*          ent    = (uint2*)alloc((size_t)(EE + NN) * 8);
    unsigned short* Wt1    = (unsigned short*)alloc((size_t)FD * FD * 2);
    unsigned short* Wt2    = (unsigned short*)alloc((size_t)FD * FD * 2);
    unsigned short* hA     = (unsigned short*)alloc((size_t)NN * FD * 2);
    unsigned short* hB     = (unsigned short*)alloc((size_t)NN * FD * 2);
    float*          bufC   = (float*)alloc((size_t)NN * OUTD * 4);
    float*          bufD   = (float*)alloc((size_t)NN * OUTD * 4);
    int*            bsum   = (int*)  alloc((size_t)NB * 4);
    int*            bflag  = (int*)  alloc((size_t)NB * 4);
    int*            gstart = (int*)  alloc((size_t)(GG + 1) * 4);
    (void)ws_size; (void)in_sizes; (void)n_in; (void)out_size;

    const int B = 256;
    // prep: weight transpose + scan-flag zero
    k_prep   <<<(FD * FD + B - 1) / B, B, 0, stream>>>(W1, W2, Wt1, Wt2, bflag);
    // fused: layer-1 GEMM || per-chunk bucket histogram || graph bounds (no global atomics)
    k_megaA  <<<GB + NBK + BB, B, 0, stream>>>(x, Wt1, hA, dst, cnt2d, bat, gstart);
    // bucket offsets (1 block)
    k_bscan  <<<1, B, 0, stream>>>(cnt2d, bbase);
    // scatter edges into bucket-segmented records
    k_scatter<<<NBK, B, 0, stream>>>(src, dst, ew, cnt2d, bbase, rec);
    // per-bucket ranks + per-node counts + weighted degrees (LDS atomics only)
    k_rank   <<<NBU, 1024, 0, stream>>>(rec, bbase, rankb, cnt_g, wdeg_g);
    // lookback scan: rowptr + dinv + self-loop entries
    k_scan   <<<NB, 1024, 0, stream>>>(cnt_g, wdeg_g, rowptr, dinv, ent, bsum, bflag, NN);
    // final CSR fill (coalesced reads, localized writes)
    k_fill2  <<<NBU, 1024, 0, stream>>>(rec, rankb, bbase, rowptr, dinv, ent);

    // layer 1 aggregation
    k_spmm_bf<<<(NN * 64 + B - 1) / B, B, 0, stream>>>(rowptr, ent, hA, b1, hB, NN, 1);
    // layer 2
    k_gemm_bf<<<GB, B, 0, stream>>>(hB, Wt2, hA, NN);
    k_spmm_bf<<<(NN * 64 + B - 1) / B, B, 0, stream>>>(rowptr, ent, hA, b2, hB, NN, 1);
    // layer 3
    k_gemm10 <<<(NN + B - 1) / B, B, 0, stream>>>(hB, W3, bufC, NN);
    k_spmm10 <<<(NN * OUTD + B - 1) / B, B, 0, stream>>>(rowptr, ent, bufC, b3, bufD, NN);
    // pool + log_softmax
    k_poolfin<<<GG, 256, 0, stream>>>(bufD, gstart, out);
}

// Round 10
// 268.248 us; speedup vs baseline: 1.2140x; 1.0505x over previous
//
#include <hip/hip_runtime.h>
#include <math.h>

#define NN 50000
#define EE 800000
#define GG 64
#define FD 128
#define OUTD 10
#define GB 782          // (NN+63)/64 gemm blocks
#define BB 196          // (NN+255)/256 bounds blocks
#define NBU 196         // buckets of 256 nodes: ceil(50000/256)
#define NBK 128         // edge-chunk blocks
#define CH 6250         // edges per chunk (128*6250 = 800000 exactly)

typedef __attribute__((ext_vector_type(8))) short s8v;    // 8 bf16
typedef __attribute__((ext_vector_type(4))) float f4v;    // 4 f32 acc

static __device__ inline unsigned short f2b(float f) {    // f32 -> bf16 RNE
    unsigned int u = __float_as_uint(f);
    return (unsigned short)((u + 0x7FFFu + ((u >> 16) & 1u)) >> 16);
}

// ---------------- prep: transpose weights ----------------

__global__ void k_prep(const float* __restrict__ W1, const float* __restrict__ W2,
                       unsigned short* __restrict__ Wt1, unsigned short* __restrict__ Wt2) {
    int i = blockIdx.x * blockDim.x + threadIdx.x;
    if (i < FD * FD) {
        int nn = i >> 7, k = i & 127;
        Wt1[i] = f2b(W1[k * FD + nn]);
        Wt2[i] = f2b(W2[k * FD + nn]);
    }
}

// ---------------- mega kernel: gemm1 || bucket-histogram || bounds ----------------

static __device__ inline void gemm_f32in_body(int bid, const float* __restrict__ A,
        const unsigned short* __restrict__ Wt, unsigned short* __restrict__ out, int n) {
    int tid = threadIdx.x;
    int wave = tid >> 6, lane = tid & 63;
    int quad = lane >> 4, c16 = lane & 15;
    int rowbase = bid * 64 + wave * 16;
    int rowA = rowbase + c16;
    if (rowA >= n) rowA = n - 1;
    f4v acc[8];
    #pragma unroll
    for (int t = 0; t < 8; ++t) acc[t] = (f4v){0.f, 0.f, 0.f, 0.f};
    #pragma unroll
    for (int k0 = 0; k0 < 128; k0 += 32) {
        const float* ap = A + (size_t)rowA * FD + k0 + quad * 8;
        float4 a0 = *(const float4*)ap;
        float4 a1 = *(const float4*)(ap + 4);
        s8v a;
        a[0] = (short)f2b(a0.x); a[1] = (short)f2b(a0.y);
        a[2] = (short)f2b(a0.z); a[3] = (short)f2b(a0.w);
        a[4] = (short)f2b(a1.x); a[5] = (short)f2b(a1.y);
        a[6] = (short)f2b(a1.z); a[7] = (short)f2b(a1.w);
        #pragma unroll
        for (int t = 0; t < 8; ++t) {
            s8v b = *(const s8v*)(Wt + (size_t)(t * 16 + c16) * FD + k0 + quad * 8);
            acc[t] = __builtin_amdgcn_mfma_f32_16x16x32_bf16(a, b, acc[t], 0, 0, 0);
        }
    }
    #pragma unroll
    for (int t = 0; t < 8; ++t) {
        #pragma unroll
        for (int r = 0; r < 4; ++r) {
            int row = rowbase + quad * 4 + r;
            if (row < n) out[(size_t)row * FD + t * 16 + c16] = f2b(acc[t][r]);
        }
    }
}

__global__ __launch_bounds__(256) void k_megaA(const float* __restrict__ x,
        const unsigned short* __restrict__ Wt1, unsigned short* __restrict__ hA,
        const int* __restrict__ dst, int* __restrict__ cnt2d,
        const int* __restrict__ batch, int* __restrict__ gstart) {
    int b = blockIdx.x;
    int tid = threadIdx.x;
    if (b < GB) {
        gemm_f32in_body(b, x, Wt1, hA, NN);
    } else if (b < GB + NBK) {
        // per-chunk bucket histogram (LDS); store transposed [bucket][blk]
        __shared__ unsigned hist[NBU];
        int blk = b - GB;
        if (tid < NBU) hist[tid] = 0;
        __syncthreads();
        int e0 = blk * CH;
        for (int e = e0 + tid; e < e0 + CH; e += 256)
            atomicAdd(&hist[(unsigned)dst[e] >> 8], 1u);
        __syncthreads();
        if (tid < NBU) cnt2d[tid * NBK + blk] = (int)hist[tid];
    } else {
        int i = (b - GB - NBK) * 256 + tid;
        if (i < NN) {
            int bb = batch[i];
            int bp = (i == 0) ? -1 : batch[i - 1];
            for (int g = bp + 1; g <= bb; ++g) gstart[g] = i;
            if (i == NN - 1)
                for (int g = bb + 1; g <= GG; ++g) gstart[g] = NN;
        }
    }
}

// ---------------- scatter (with replicated bucket-scan, no extra launch) ----------------
// rec[slot] = ( (d&255)<<16 | src , bits(w) );  LDS cursors only.

__global__ __launch_bounds__(256) void k_scatter(const int* __restrict__ src,
        const int* __restrict__ dst, const float* __restrict__ ew,
        const int* __restrict__ cnt2d, int* __restrict__ bbase_g,
        uint2* __restrict__ rec) {
    __shared__ int colsum[NBU];
    __shared__ int ownoff[NBU];
    __shared__ unsigned cur[NBU];
    __shared__ int wtot_s[4];
    int tid = threadIdx.x;
    int blk = blockIdx.x;
    // each thread (bucket) streams its 128 per-block counts from L2
    if (tid < NBU) {
        const int* c = cnt2d + tid * NBK;
        int own = 0, tot = 0;
        for (int b = 0; b < NBK; ++b) {
            int t = c[b];
            if (b < blk) own += t;
            tot += t;
        }
        ownoff[tid] = own;
        colsum[tid] = tot;
    }
    __syncthreads();
    // exclusive scan of colsum[196] -> bucket bases (4-wave shfl scan)
    {
        int lane = tid & 63, wv = tid >> 6;
        int v = (tid < NBU) ? colsum[tid] : 0;
        int s = v;
        #pragma unroll
        for (int off = 1; off < 64; off <<= 1) {
            int u = __shfl_up(s, off, 64);
            if (lane >= off) s += u;
        }
        if (lane == 63) wtot_s[wv] = s;
        __syncthreads();
        int pre = 0;
        for (int j = 0; j < wv; ++j) pre += wtot_s[j];
        int base = pre + s - v;    // exclusive
        if (tid < NBU) {
            cur[tid] = (unsigned)(base + ownoff[tid]);
            if (blk == 0) bbase_g[tid] = base;
        }
        if (blk == 0 && tid == NBU - 1) bbase_g[NBU] = base + v;
    }
    __syncthreads();
    int e0 = blk * CH;
    for (int e = e0 + tid; e < e0 + CH; e += 256) {
        int d = dst[e];
        unsigned bkt = (unsigned)d >> 8;
        unsigned pos = atomicAdd(&cur[bkt], 1u);
        rec[pos] = make_uint2(((unsigned)(d & 255) << 16) | (unsigned)src[e],
                              __float_as_uint(ew[e]));
    }
}

// ---------------- per-bucket: rank + rowptr + dinv + self-loop ent (no global scan) ----------------
// rowptr[i] = bbase[b] + i + excl_scan_within_bucket(cnt)

__global__ __launch_bounds__(1024) void k_rank(const uint2* __restrict__ rec,
        const int* __restrict__ bbase, unsigned short* __restrict__ rankb,
        int* __restrict__ rowptr, float* __restrict__ dinv, uint2* __restrict__ ent) {
    __shared__ unsigned cntS[256];
    __shared__ float wdegS[256];
    __shared__ int wtot_s[4];
    int b = blockIdx.x;
    int tid = threadIdx.x;
    if (tid < 256) { cntS[tid] = 0; wdegS[tid] = 0.0f; }
    __syncthreads();
    int beg = bbase[b], end = bbase[b + 1];
    for (int s = beg + tid; s < end; s += 1024) {
        uint2 r = rec[s];
        unsigned dl = r.x >> 16;
        unsigned old = atomicAdd(&cntS[dl], 1u);
        rankb[s] = (unsigned short)old;
        atomicAdd(&wdegS[dl], __uint_as_float(r.y));
    }
    __syncthreads();
    if (tid < 256) {
        int lane = tid & 63, wv = tid >> 6;
        int v = (int)cntS[tid];
        int s = v;
        #pragma unroll
        for (int off = 1; off < 64; off <<= 1) {
            int u = __shfl_up(s, off, 64);
            if (lane >= off) s += u;
        }
        if (lane == 63) wtot_s[wv] = s;
        __syncthreads();
        int pre = 0;
        for (int j = 0; j < wv; ++j) pre += wtot_s[j];
        int excl = pre + s - v;
        int node = b * 256 + tid;
        if (node < NN) {
            int r = beg + node + excl;           // += i self-loops before node
            rowptr[node] = r;
            float di = 1.0f / sqrtf(wdegS[tid] + 1.0f);
            dinv[node] = di;
            ent[r + v] = make_uint2((unsigned)node, __float_as_uint(di * di));
        }
        if (node == NN - 1) rowptr[NN] = EE + NN;
    }
}

// ---------------- final CSR fill: coalesced reads, bucket-localized ent writes ----------------

__global__ __launch_bounds__(1024) void k_fill2(const uint2* __restrict__ rec,
        const unsigned short* __restrict__ rankb, const int* __restrict__ bbase,
        const int* __restrict__ rowptr, const float* __restrict__ dinv,
        uint2* __restrict__ ent) {
    int b = blockIdx.x;
    int tid = threadIdx.x;
    int beg = bbase[b], end = bbase[b + 1];
    for (int s = beg + tid; s < end; s += 1024) {
        uint2 r = rec[s];
        unsigned sn = r.x & 0xFFFFu;
        int d = (b << 8) | (int)(r.x >> 16);
        int pos = rowptr[d] + (int)rankb[s];
        float val = dinv[sn] * __uint_as_float(r.y) * dinv[d];
        ent[pos] = make_uint2(sn, __float_as_uint(val));
    }
}

// ---------------- dense transform: bf16 MFMA GEMM (bf16 in) ----------------

__global__ __launch_bounds__(256) void k_gemm_bf(const unsigned short* __restrict__ A,
        const unsigned short* __restrict__ Wt, unsigned short* __restrict__ out, int n) {
    int tid = threadIdx.x;
    int wave = tid >> 6, lane = tid & 63;
    int quad = lane >> 4, c16 = lane & 15;
    int rowbase = blockIdx.x * 64 + wave * 16;
    int rowA = rowbase + c16;
    if (rowA >= n) rowA = n - 1;
    f4v acc[8];
    #pragma unroll
    for (int t = 0; t < 8; ++t) acc[t] = (f4v){0.f, 0.f, 0.f, 0.f};
    #pragma unroll
    for (int k0 = 0; k0 < 128; k0 += 32) {
        s8v a = *(const s8v*)(A + (size_t)rowA * FD + k0 + quad * 8);
        #pragma unroll
        for (int t = 0; t < 8; ++t) {
            s8v b = *(const s8v*)(Wt + (size_t)(t * 16 + c16) * FD + k0 + quad * 8);
            acc[t] = __builtin_amdgcn_mfma_f32_16x16x32_bf16(a, b, acc[t], 0, 0, 0);
        }
    }
    #pragma unroll
    for (int t = 0; t < 8; ++t) {
        #pragma unroll
        for (int r = 0; r < 4; ++r) {
            int row = rowbase + quad * 4 + r;
            if (row < n) out[(size_t)row * FD + t * 16 + c16] = f2b(acc[t][r]);
        }
    }
}

// out[n][10] = A[n][128] @ W[128][10], A bf16, W f32 (LDS), out f32
__global__ void k_gemm10(const unsigned short* __restrict__ A, const float* __restrict__ W,
                         float* __restrict__ out, int n) {
    __shared__ float Ws[FD * OUTD];
    int tid = threadIdx.x;
    for (int i = tid; i < FD * OUTD; i += blockDim.x) Ws[i] = W[i];
    __syncthreads();
    int i = blockIdx.x * blockDim.x + tid;
    if (i >= n) return;
    float acc[OUTD];
    #pragma unroll
    for (int c = 0; c < OUTD; ++c) acc[c] = 0.0f;
    const unsigned short* a = A + (size_t)i * FD;
    for (int k0 = 0; k0 < FD; k0 += 8) {
        uint4 t = *(const uint4*)(a + k0);
        float av[8];
        av[0] = __uint_as_float(t.x << 16); av[1] = __uint_as_float(t.x & 0xFFFF0000u);
        av[2] = __uint_as_float(t.y << 16); av[3] = __uint_as_float(t.y & 0xFFFF0000u);
        av[4] = __uint_as_float(t.z << 16); av[5] = __uint_as_float(t.z & 0xFFFF0000u);
        av[6] = __uint_as_float(t.w << 16); av[7] = __uint_as_float(t.w & 0xFFFF0000u);
        #pragma unroll
        for (int j = 0; j < 8; ++j)
            #pragma unroll
            for (int c = 0; c < OUTD; ++c) acc[c] += av[j] * Ws[(k0 + j) * OUTD + c];
    }
    float* o = out + (size_t)i * OUTD;
    #pragma unroll
    for (int c = 0; c < OUTD; ++c) o[c] = acc[c];
}

// ---------------- sparse aggregation, bf16 features ----------------
// one wave per node; full 16-edge iterations + 4-grain tail (no wasted gathers)
__global__ __launch_bounds__(256) void k_spmm_bf(const int* __restrict__ rowptr,
        const uint2* __restrict__ ent, const unsigned short* __restrict__ tin,
        const float* __restrict__ bias, unsigned short* __restrict__ out,
        int n, int dorelu) {
    int w = (blockIdx.x * blockDim.x + threadIdx.x) >> 6;
    int lane = threadIdx.x & 63;
    if (w >= n) return;
    int c = lane & 15, g = lane >> 4;
    int beg = rowptr[w], end = rowptr[w + 1];
    float acc[8];
    #pragma unroll
    for (int j = 0; j < 8; ++j) acc[j] = 0.0f;
    int e0 = beg;
    for (; e0 + 16 <= end; e0 += 16) {           // full iterations: all loads real
        uint2 en[4];
        uint4 t[4];
        #pragma unroll
        for (int u = 0; u < 4; ++u) en[u] = ent[e0 + 4 * u + g];
        #pragma unroll
        for (int u = 0; u < 4; ++u)
            t[u] = *(const uint4*)(tin + (size_t)en[u].x * FD + c * 8);
        #pragma unroll
        for (int u = 0; u < 4; ++u) {
            float v = __uint_as_float(en[u].y);
            acc[0] += v * __uint_as_float(t[u].x << 16);
            acc[1] += v * __uint_as_float(t[u].x & 0xFFFF0000u);
            acc[2] += v * __uint_as_float(t[u].y << 16);
            acc[3] += v * __uint_as_float(t[u].y & 0xFFFF0000u);
            acc[4] += v * __uint_as_float(t[u].z << 16);
            acc[5] += v * __uint_as_float(t[u].z & 0xFFFF0000u);
            acc[6] += v * __uint_as_float(t[u].w << 16);
            acc[7] += v * __uint_as_float(t[u].w & 0xFFFF0000u);
        }
    }
    for (; e0 < end; e0 += 4) {                  // tail: 4-edge grain
        int e = e0 + g;
        uint2 en = (e < end) ? ent[e] : make_uint2(0u, 0u);
        float v = (e < end) ? __uint_as_float(en.y) : 0.0f;
        uint4 t = *(const uint4*)(tin + (size_t)en.x * FD + c * 8);
        acc[0] += v * __uint_as_float(t.x << 16);
        acc[1] += v * __uint_as_float(t.x & 0xFFFF0000u);
        acc[2] += v * __uint_as_float(t.y << 16);
        acc[3] += v * __uint_as_float(t.y & 0xFFFF0000u);
        acc[4] += v * __uint_as_float(t.z << 16);
        acc[5] += v * __uint_as_float(t.z & 0xFFFF0000u);
        acc[6] += v * __uint_as_float(t.w << 16);
        acc[7] += v * __uint_as_float(t.w & 0xFFFF0000u);
    }
    #pragma unroll
    for (int j = 0; j < 8; ++j) {
        acc[j] += __shfl_xor(acc[j], 16, 64);
        acc[j] += __shfl_xor(acc[j], 32, 64);
    }
    if (g == 0) {
        uint4 r;
        float o[8];
        #pragma unroll
        for (int j = 0; j < 8; ++j) {
            float x = acc[j] + bias[c * 8 + j];
            o[j] = dorelu ? fmaxf(x, 0.0f) : x;
        }
        r.x = (unsigned)f2b(o[0]) | ((unsigned)f2b(o[1]) << 16);
        r.y = (unsigned)f2b(o[2]) | ((unsigned)f2b(o[3]) << 16);
        r.z = (unsigned)f2b(o[4]) | ((unsigned)f2b(o[5]) << 16);
        r.w = (unsigned)f2b(o[6]) | ((unsigned)f2b(o[7]) << 16);
        *(uint4*)(out + (size_t)w * FD + c * 8) = r;
    }
}

// one thread per (node, feature), 10 features, f32 (input 2 MB -> cache-resident)
__global__ void k_spmm10(const int* __restrict__ rowptr, const uint2* __restrict__ ent,
        const float* __restrict__ tin, const float* __restrict__ bias,
        float* __restrict__ out, int n) {
    int t = blockIdx.x * blockDim.x + threadIdx.x;
    int node = t / OUTD;
    int c = t - node * OUTD;
    if (node >= n) return;
    int beg = rowptr[node], end = rowptr[node + 1];
    float acc = 0.0f;
    for (int e = beg; e < end; ++e) {
        uint2 en = ent[e];
        acc += __uint_as_float(en.y) * tin[(size_t)en.x * OUTD + c];
    }
    out[(size_t)node * OUTD + c] = acc + bias[c];
}

// ---------------- pooling + log_softmax (1 block/graph) ----------------

__global__ __launch_bounds__(256) void k_poolfin(const float* __restrict__ h,
        const int* __restrict__ gstart, float* __restrict__ out) {
    int g = blockIdx.x;
    int beg = gstart[g], end = gstart[g + 1];
    int tid = threadIdx.x;
    int lane = tid & 63, wv = tid >> 6;
    float acc[OUTD];
    #pragma unroll
    for (int c = 0; c < OUTD; ++c) acc[c] = 0.0f;
    for (int i = beg + tid; i < end; i += 256) {
        const float* hp = h + (size_t)i * OUTD;
        #pragma unroll
        for (int c = 0; c < OUTD; ++c) acc[c] += hp[c];
    }
    #pragma unroll
    for (int off = 32; off >= 1; off >>= 1)
        #pragma unroll
        for (int c = 0; c < OUTD; ++c) acc[c] += __shfl_down(acc[c], off, 64);
    __shared__ float ws[4][OUTD];
    if (lane == 0)
        #pragma unroll
        for (int c = 0; c < OUTD; ++c) ws[wv][c] = acc[c];
    __syncthreads();
    if (tid == 0) {
        float cf = fmaxf((float)(end - beg), 1.0f);
        float v[OUTD], m = -1e30f;
        #pragma unroll
        for (int c = 0; c < OUTD; ++c) {
            v[c] = (ws[0][c] + ws[1][c] + ws[2][c] + ws[3][c]) / cf;
            m = fmaxf(m, v[c]);
        }
        float s = 0.0f;
        #pragma unroll
        for (int c = 0; c < OUTD; ++c) s += expf(v[c] - m);
        float l = logf(s);
        #pragma unroll
        for (int c = 0; c < OUTD; ++c) out[g * OUTD + c] = v[c] - m - l;
    }
}

// ---------------- launcher ----------------

extern "C" void kernel_launch(void* const* d_in, const int* in_sizes, int n_in,
                              void* d_out, int out_size, void* d_ws, size_t ws_size,
                              hipStream_t stream) {
    const float* x   = (const float*)d_in[0];
    const int*   ei  = (const int*)d_in[1];
    const float* ew  = (const float*)d_in[2];
    const int*   bat = (const int*)d_in[3];
    const float* W1  = (const float*)d_in[4];
    const float* b1  = (const float*)d_in[5];
    const float* W2  = (const float*)d_in[6];
    const float* b2  = (const float*)d_in[7];
    const float* W3  = (const float*)d_in[8];
    const float* b3  = (const float*)d_in[9];
    float* out = (float*)d_out;

    const int* src = ei;
    const int* dst = ei + EE;

    char* p = (char*)d_ws;
    auto alloc = [&](size_t bytes) -> void* {
        void* r = (void*)p;
        p += (bytes + 255) & ~(size_t)255;
        return r;
    };
    int*            cnt2d  = (int*)  alloc((size_t)NBU * NBK * 4);
    int*            bbase  = (int*)  alloc((size_t)(NBU + 1) * 4);
    uint2*          rec    = (uint2*)alloc((size_t)EE * 8);
    unsigned short* rankb  = (unsigned short*)alloc((size_t)EE * 2);
    float*          dinv   = (float*)alloc((size_t)NN * 4);
    int*            rowptr = (int*)  alloc((size_t)(NN + 1) * 4);
    uint2*          ent    = (uint2*)alloc((size_t)(EE + NN) * 8);
    unsigned short* Wt1    = (unsigned short*)alloc((size_t)FD * FD * 2);
    unsigned short* Wt2    = (unsigned short*)alloc((size_t)FD * FD * 2);
    unsigned short* hA     = (unsigned short*)alloc((size_t)NN * FD * 2);
    unsigned short* hB     = (unsigned short*)alloc((size_t)NN * FD * 2);
    float*          bufC   = (float*)alloc((size_t)NN * OUTD * 4);
    float*          bufD   = (float*)alloc((size_t)NN * OUTD * 4);
    int*            gstart = (int*)  alloc((size_t)(GG + 1) * 4);
    (void)ws_size; (void)in_sizes; (void)n_in; (void)out_size;

    const int B = 256;
    // prep: weight transpose
    k_prep   <<<(FD * FD + B - 1) / B, B, 0, stream>>>(W1, W2, Wt1, Wt2);
    // fused: layer-1 GEMM || per-chunk bucket histogram || graph bounds
    k_megaA  <<<GB + NBK + BB, B, 0, stream>>>(x, Wt1, hA, dst, cnt2d, bat, gstart);
    // scatter (replicated bucket-scan inside) -> bucket-segmented records
    k_scatter<<<NBK, B, 0, stream>>>(src, dst, ew, cnt2d, bbase, rec);
    // per-bucket ranks + rowptr + dinv + self-loop entries (LDS only)
    k_rank   <<<NBU, 1024, 0, stream>>>(rec, bbase, rankb, rowptr, dinv, ent);
    // final CSR fill
    k_fill2  <<<NBU, 1024, 0, stream>>>(rec, rankb, bbase, rowptr, dinv, ent);

    // layer 1 aggregation
    k_spmm_bf<<<(NN * 64 + B - 1) / B, B, 0, stream>>>(rowptr, ent, hA, b1, hB, NN, 1);
    // layer 2
    k_gemm_bf<<<GB, B, 0, stream>>>(hB, Wt2, hA, NN);
    k_spmm_bf<<<(NN * 64 + B - 1) / B, B, 0, stream>>>(rowptr, ent, hA, b2, hB, NN, 1);
    // layer 3
    k_gemm10 <<<(NN + B - 1) / B, B, 0, stream>>>(hB, W3, bufC, NN);
    k_spmm10 <<<(NN * OUTD + B - 1) / B, B, 0, stream>>>(rowptr, ent, bufC, b3, bufD, NN);
    // pool + log_softmax
    k_poolfin<<<GG, 256, 0, stream>>>(bufD, gstart, out);
}